// Round 2
// baseline (270.614 us; speedup 1.0000x reference)
//
#include <hip/hip_runtime.h>
#include <stdint.h>

#define D_DIM          4096
#define ROWS_PER_BLOCK 4        // 4 waves per 256-thread block, one row per wave

__device__ __forceinline__ uint32_t wave_reduce_min(uint32_t v) {
    #pragma unroll
    for (int m = 32; m >= 1; m >>= 1) {
        uint32_t o = (uint32_t)__shfl_xor((int)v, m, 64);
        v = (o < v) ? o : v;
    }
    return v;
}
__device__ __forceinline__ uint32_t wave_reduce_max(uint32_t v) {
    #pragma unroll
    for (int m = 32; m >= 1; m >>= 1) {
        uint32_t o = (uint32_t)__shfl_xor((int)v, m, 64);
        v = (o > v) ? o : v;
    }
    return v;
}

__global__ __launch_bounds__(256)
void kwta_kernel(const float* __restrict__ x, const int* __restrict__ kptr,
                 float* __restrict__ out) {
    const int wid  = threadIdx.x >> 6;     // wave id within block
    const int lane = threadIdx.x & 63;
    const int row  = blockIdx.x * ROWS_PER_BLOCK + wid;
    const size_t base = (size_t)row * D_DIM;
    const float4* __restrict__ xr = reinterpret_cast<const float4*>(x + base);
    float4* __restrict__ orow     = reinterpret_cast<float4*>(out + base);
    const int k = kptr[0];

    // 64 elements per lane: 16 coalesced float4 loads, mapped to
    // order-preserving uint32 (monotone: a<b as float <=> map(a)<map(b) as uint).
    uint32_t u[64];
    #pragma unroll
    for (int j = 0; j < 16; ++j) {
        float4 v = xr[lane + j * 64];
        uint32_t b[4] = { __float_as_uint(v.x), __float_as_uint(v.y),
                          __float_as_uint(v.z), __float_as_uint(v.w) };
        #pragma unroll
        for (int e = 0; e < 4; ++e) {
            uint32_t f = b[e];
            u[j * 4 + e] = ((int32_t)f < 0) ? ~f : (f | 0x80000000u);
        }
    }

    // Row min/max to tighten the bisection range (wave-local, no LDS).
    uint32_t mn = 0xFFFFFFFFu, mx = 0u;
    #pragma unroll
    for (int e = 0; e < 64; ++e) {
        mn = (u[e] < mn) ? u[e] : mn;
        mx = (u[e] > mx) ? u[e] : mx;
    }
    uint32_t lo = wave_reduce_min(mn);
    uint32_t hi = wave_reduce_max(mx);

    // Bisect on the bit pattern: find largest t with count(u >= t) >= k.
    // Counting via ballot -> scalar popcount: VALU cost is 64 v_cmp per iter.
    #pragma unroll 1
    while (lo < hi) {
        uint32_t diff = hi - lo;
        uint32_t mid  = lo + (diff >> 1) + (diff & 1u);  // upper mid, overflow-safe
        int c = 0;
        #pragma unroll
        for (int e = 0; e < 64; ++e)
            c += (int)__popcll(__ballot(u[e] >= mid));
        if (c >= k) lo = mid; else hi = mid - 1u;
    }

    const uint32_t thr = lo;
    // Write output from registers (x is never re-read).
    #pragma unroll
    for (int j = 0; j < 16; ++j) {
        float4 o;
        float* po = &o.x;
        #pragma unroll
        for (int e = 0; e < 4; ++e) {
            uint32_t uu = u[j * 4 + e];
            uint32_t f  = (uu & 0x80000000u) ? (uu ^ 0x80000000u) : ~uu;
            po[e] = (uu >= thr) ? __uint_as_float(f) : 0.0f;
        }
        orow[lane + j * 64] = o;
    }
}

extern "C" void kernel_launch(void* const* d_in, const int* in_sizes, int n_in,
                              void* d_out, int out_size, void* d_ws, size_t ws_size,
                              hipStream_t stream) {
    const float* x    = (const float*)d_in[0];
    const int*   kptr = (const int*)d_in[1];
    float*       out  = (float*)d_out;
    const int rows   = out_size / D_DIM;            // 8192
    const int blocks = rows / ROWS_PER_BLOCK;       // 2048
    kwta_kernel<<<blocks, 256, 0, stream>>>(x, kptr, out);
}

// Round 3
// 235.343 us; speedup vs baseline: 1.1499x; 1.1499x over previous
//
#include <hip/hip_runtime.h>
#include <stdint.h>

#define D_DIM   4096
#define THREADS 256          // one block per row; 4 waves; 16 elems/thread

__global__ __launch_bounds__(THREADS, 8)
void kwta_kernel(const float* __restrict__ x, const int* __restrict__ kptr,
                 float* __restrict__ out) {
    __shared__ uint32_t hist[2][256];     // double-buffered per-level histogram

    const int t    = threadIdx.x;
    const int lane = t & 63;
    const int row  = blockIdx.x;
    const size_t base = (size_t)row * D_DIM;
    const float4* __restrict__ xr = reinterpret_cast<const float4*>(x + base);
    float4* __restrict__ orow     = reinterpret_cast<float4*>(out + base);
    int k = kptr[0];

    // Load 16 elements (coalesced float4), map to order-preserving uint32:
    // a < b (float) <=> map(a) < map(b) (uint).
    uint32_t u[16];
    #pragma unroll
    for (int j = 0; j < 4; ++j) {
        float4 v = xr[t + j * THREADS];
        uint32_t b[4] = { __float_as_uint(v.x), __float_as_uint(v.y),
                          __float_as_uint(v.z), __float_as_uint(v.w) };
        #pragma unroll
        for (int e = 0; e < 4; ++e) {
            uint32_t f = b[e];
            u[j * 4 + e] = ((int32_t)f < 0) ? ~f : (f | 0x80000000u);
        }
    }

    // 4-level radix select (8 bits / level), MSB first.
    uint32_t pref = 0, maskHi = 0;
    int shift = 24;
    #pragma unroll
    for (int L = 0; L < 4; ++L) {
        uint32_t* __restrict__ h = hist[L & 1];
        h[t] = 0;
        __syncthreads();
        #pragma unroll
        for (int e = 0; e < 16; ++e) {
            if ((u[e] & maskHi) == pref)
                atomicAdd(&h[(u[e] >> shift) & 0xFFu], 1u);
        }
        __syncthreads();

        // Every wave redundantly finds the selected bin (no cross-wave sync).
        // Lane owns bins 4*lane .. 4*lane+3.
        uint4 hv = *reinterpret_cast<const uint4*>(&h[lane * 4]);
        uint32_t s3 = hv.w;              // local suffix sums
        uint32_t s2 = hv.z + s3;
        uint32_t s1 = hv.y + s2;
        uint32_t s0 = hv.x + s1;
        // wave inclusive suffix scan of per-lane block sums
        uint32_t W = s0;
        #pragma unroll
        for (int m = 1; m <= 32; m <<= 1) {
            uint32_t o = (uint32_t)__shfl_down((int)W, m, 64);
            if (lane + m < 64) W += o;
        }
        const uint32_t above = W - s0;   // sum over lanes > lane
        const uint32_t S0 = above + s0, S1 = above + s1,
                       S2 = above + s2, S3 = above + s3;
        const uint32_t uk = (uint32_t)k;
        // largest bin index (within this lane's 4) whose suffix count >= k
        int bi = -1;
        if      (S3 >= uk) bi = 3;
        else if (S2 >= uk) bi = 2;
        else if (S1 >= uk) bi = 1;
        else if (S0 >= uk) bi = 0;
        uint32_t key = 0;                // pack (bin<<24)|S[bin+1]; S[bin+1] < k <= 4096
        if (bi >= 0) {
            uint32_t b  = (uint32_t)(lane * 4 + bi);
            uint32_t Sb = (bi == 0) ? S0 : (bi == 1) ? S1 : (bi == 2) ? S2 : S3;
            uint32_t hb = (bi == 0) ? hv.x : (bi == 1) ? hv.y : (bi == 2) ? hv.z : hv.w;
            key = (b << 24) | (Sb - hb);
        }
        #pragma unroll
        for (int m = 32; m >= 1; m >>= 1) {
            uint32_t o = (uint32_t)__shfl_xor((int)key, m, 64);
            key = (o > key) ? o : key;
        }
        const uint32_t b = key >> 24;
        k -= (int)(key & 0xFFFFFFu);     // k -= S[b+1] (count with digit > b)
        pref   |= b << shift;
        maskHi |= 0xFFu << shift;
        shift  -= 8;
    }

    const uint32_t thr = pref;           // exact bit pattern of k-th largest
    #pragma unroll
    for (int j = 0; j < 4; ++j) {
        float4 o;
        float* po = &o.x;
        #pragma unroll
        for (int e = 0; e < 4; ++e) {
            uint32_t uu = u[j * 4 + e];
            uint32_t f  = (uu & 0x80000000u) ? (uu ^ 0x80000000u) : ~uu;
            po[e] = (uu >= thr) ? __uint_as_float(f) : 0.0f;
        }
        orow[t + j * THREADS] = o;
    }
}

extern "C" void kernel_launch(void* const* d_in, const int* in_sizes, int n_in,
                              void* d_out, int out_size, void* d_ws, size_t ws_size,
                              hipStream_t stream) {
    const float* x    = (const float*)d_in[0];
    const int*   kptr = (const int*)d_in[1];
    float*       out  = (float*)d_out;
    const int rows = out_size / D_DIM;   // 8192
    kwta_kernel<<<rows, THREADS, 0, stream>>>(x, kptr, out);
}

// Round 4
// 232.008 us; speedup vs baseline: 1.1664x; 1.0144x over previous
//
#include <hip/hip_runtime.h>
#include <stdint.h>

#define D_DIM   4096
#define THREADS 256
#define NBINS   4096          // 12-bit first digit

__global__ __launch_bounds__(THREADS, 8)
void kwta_kernel(const float* __restrict__ x, const int* __restrict__ kptr,
                 float* __restrict__ out) {
    __shared__ uint32_t hist[NBINS];      // 16 KB; reused as survivor buffer
    __shared__ uint32_t wtot[4];
    __shared__ int pub_bin, pub_kp, ns;

    const int t    = threadIdx.x;
    const int wid  = t >> 6;
    const int lane = t & 63;
    const int row  = blockIdx.x;
    const size_t base = (size_t)row * D_DIM;
    const float4* __restrict__ xr = reinterpret_cast<const float4*>(x + base);
    float4* __restrict__ orow     = reinterpret_cast<float4*>(out + base);
    const int k = kptr[0];

    // Load 16 elements (coalesced float4), map to order-preserving uint32.
    uint32_t u[16];
    #pragma unroll
    for (int j = 0; j < 4; ++j) {
        float4 v = xr[t + j * THREADS];
        uint32_t b[4] = { __float_as_uint(v.x), __float_as_uint(v.y),
                          __float_as_uint(v.z), __float_as_uint(v.w) };
        #pragma unroll
        for (int e = 0; e < 4; ++e) {
            uint32_t f = b[e];
            u[j * 4 + e] = ((int32_t)f < 0) ? ~f : (f | 0x80000000u);
        }
    }

    // Zero histogram (16 words/thread via uint4) + survivor counter.
    #pragma unroll
    for (int j = 0; j < 4; ++j)
        reinterpret_cast<uint4*>(hist)[t + j * THREADS] = make_uint4(0, 0, 0, 0);
    if (t == 0) ns = 0;
    __syncthreads();                                   // B1

    // 12-bit histogram of the top bits (low contention: mantissa bits spread).
    #pragma unroll
    for (int e = 0; e < 16; ++e)
        atomicAdd(&hist[u[e] >> 20], 1u);
    __syncthreads();                                   // B2

    // Cooperative suffix scan: thread t owns bins [16t, 16t+16).
    uint32_t h[16];
    #pragma unroll
    for (int j = 0; j < 4; ++j) {
        uint4 hv = reinterpret_cast<const uint4*>(hist)[4 * t + j];
        h[4 * j + 0] = hv.x; h[4 * j + 1] = hv.y;
        h[4 * j + 2] = hv.z; h[4 * j + 3] = hv.w;
    }
    uint32_t T = 0;
    #pragma unroll
    for (int i = 0; i < 16; ++i) T += h[i];
    // wave inclusive suffix scan of T
    uint32_t W = T;
    #pragma unroll
    for (int m = 1; m <= 32; m <<= 1) {
        uint32_t o = (uint32_t)__shfl_down((int)W, m, 64);
        if (lane + m < 64) W += o;
    }
    if (lane == 0) wtot[wid] = W;                      // wave total
    __syncthreads();                                   // B3
    uint32_t above = W - T;                            // lanes above, same wave
    #pragma unroll
    for (int w = 0; w < 4; ++w)
        if (w > wid) above += wtot[w];
    // k-th largest lies in exactly one thread's bin range.
    if (above < (uint32_t)k && (uint32_t)k <= above + T) {
        uint32_t cum = above;
        #pragma unroll
        for (int i = 15; i >= 0; --i) {
            cum += h[i];
            if (cum >= (uint32_t)k) {
                pub_bin = 16 * t + i;
                pub_kp  = k - (int)(cum - h[i]);       // residual rank in bin
                break;
            }
        }
    }
    __syncthreads();                                   // B4
    const uint32_t bin = (uint32_t)pub_bin;
    const int kp = pub_kp;

    // Extract survivors (digit == bin) into hist buffer (reused).
    #pragma unroll
    for (int e = 0; e < 16; ++e) {
        const bool m = (u[e] >> 20) == bin;
        unsigned long long mk = __ballot(m);
        int cnt = (int)__popcll(mk);
        int bs = 0;
        if (lane == 0 && cnt) bs = atomicAdd(&ns, cnt);
        bs = __shfl(bs, 0, 64);
        if (m) {
            int pos = bs + (int)__popcll(mk & ((1ull << lane) - 1ull));
            hist[pos] = u[e];
        }
    }
    __syncthreads();                                   // B5
    const int N = ns;

    // Sub-select kp-th largest among N survivors by low-20 bits.
    // Redundant per wave (no barriers). mid >= 1 always, so sentinel 0 is inert.
    uint32_t lo = 0, hi = 0xFFFFFu;
    if (N <= 256) {
        uint32_t v[4];
        #pragma unroll
        for (int c = 0; c < 4; ++c) {
            int idx = 64 * c + lane;
            v[c] = (idx < N) ? (hist[idx] & 0xFFFFFu) : 0u;
        }
        #pragma unroll 1
        while (lo < hi) {
            uint32_t mid = lo + ((hi - lo + 1u) >> 1);
            int c = 0;
            #pragma unroll
            for (int j = 0; j < 4; ++j)
                c += (int)__popcll(__ballot(v[j] >= mid));
            if (c >= kp) lo = mid; else hi = mid - 1u;
        }
    } else {
        #pragma unroll 1
        while (lo < hi) {
            uint32_t mid = lo + ((hi - lo + 1u) >> 1);
            int c = 0;
            for (int cb = 0; cb < N; cb += 64) {
                uint32_t vv = 0;
                if (cb + lane < N) vv = hist[cb + lane] & 0xFFFFFu;
                c += (int)__popcll(__ballot(vv >= mid));
            }
            if (c >= kp) lo = mid; else hi = mid - 1u;
        }
    }
    const uint32_t thr = (bin << 20) | lo;             // exact k-th largest pattern

    // Write output from registers.
    #pragma unroll
    for (int j = 0; j < 4; ++j) {
        float4 o;
        float* po = &o.x;
        #pragma unroll
        for (int e = 0; e < 4; ++e) {
            uint32_t uu = u[j * 4 + e];
            uint32_t f  = (uu & 0x80000000u) ? (uu ^ 0x80000000u) : ~uu;
            po[e] = (uu >= thr) ? __uint_as_float(f) : 0.0f;
        }
        orow[t + j * THREADS] = o;
    }
}

extern "C" void kernel_launch(void* const* d_in, const int* in_sizes, int n_in,
                              void* d_out, int out_size, void* d_ws, size_t ws_size,
                              hipStream_t stream) {
    const float* x    = (const float*)d_in[0];
    const int*   kptr = (const int*)d_in[1];
    float*       out  = (float*)d_out;
    const int rows = out_size / D_DIM;   // 8192
    kwta_kernel<<<rows, THREADS, 0, stream>>>(x, kptr, out);
}

// Round 5
// 230.021 us; speedup vs baseline: 1.1765x; 1.0086x over previous
//
#include <hip/hip_runtime.h>
#include <stdint.h>

#define D_DIM   4096
#define THREADS 256
#define NBINS   4096          // 12-bit first digit

__global__ __launch_bounds__(THREADS, 8)
void kwta_kernel(const float* __restrict__ x, const int* __restrict__ kptr,
                 float* __restrict__ out) {
    __shared__ uint32_t hist[NBINS];      // 16 KB; reused as survivor buffer
    __shared__ uint32_t wtot[4];
    __shared__ int pub_bin, pub_kp, ns;

    const int t    = threadIdx.x;
    const int wid  = t >> 6;
    const int lane = t & 63;
    const int row  = blockIdx.x;
    const size_t base = (size_t)row * D_DIM;
    const float4* __restrict__ xr = reinterpret_cast<const float4*>(x + base);
    float4* __restrict__ orow     = reinterpret_cast<float4*>(out + base);
    const int k = kptr[0];

    // Load 16 elements (coalesced float4), map to order-preserving uint32.
    uint32_t u[16];
    #pragma unroll
    for (int j = 0; j < 4; ++j) {
        float4 v = xr[t + j * THREADS];
        uint32_t b[4] = { __float_as_uint(v.x), __float_as_uint(v.y),
                          __float_as_uint(v.z), __float_as_uint(v.w) };
        #pragma unroll
        for (int e = 0; e < 4; ++e) {
            uint32_t f = b[e];
            u[j * 4 + e] = ((int32_t)f < 0) ? ~f : (f | 0x80000000u);
        }
    }

    // Zero histogram (16 words/thread via uint4) + survivor counter.
    #pragma unroll
    for (int j = 0; j < 4; ++j)
        reinterpret_cast<uint4*>(hist)[t + j * THREADS] = make_uint4(0, 0, 0, 0);
    if (t == 0) ns = 0;
    __syncthreads();                                   // B1

    // 12-bit histogram of the top bits (low contention: mantissa bits spread).
    #pragma unroll
    for (int e = 0; e < 16; ++e)
        atomicAdd(&hist[u[e] >> 20], 1u);
    __syncthreads();                                   // B2

    // Cooperative suffix scan: thread t owns bins [16t, 16t+16).
    uint32_t h[16];
    #pragma unroll
    for (int j = 0; j < 4; ++j) {
        uint4 hv = reinterpret_cast<const uint4*>(hist)[4 * t + j];
        h[4 * j + 0] = hv.x; h[4 * j + 1] = hv.y;
        h[4 * j + 2] = hv.z; h[4 * j + 3] = hv.w;
    }
    uint32_t T = 0;
    #pragma unroll
    for (int i = 0; i < 16; ++i) T += h[i];
    // wave inclusive suffix scan of T
    uint32_t W = T;
    #pragma unroll
    for (int m = 1; m <= 32; m <<= 1) {
        uint32_t o = (uint32_t)__shfl_down((int)W, m, 64);
        if (lane + m < 64) W += o;
    }
    if (lane == 0) wtot[wid] = W;                      // wave total
    __syncthreads();                                   // B3
    uint32_t above = W - T;                            // lanes above, same wave
    #pragma unroll
    for (int w = 0; w < 4; ++w)
        if (w > wid) above += wtot[w];
    // k-th largest lies in exactly one thread's bin range.
    if (above < (uint32_t)k && (uint32_t)k <= above + T) {
        uint32_t cum = above;
        #pragma unroll
        for (int i = 15; i >= 0; --i) {
            cum += h[i];
            if (cum >= (uint32_t)k) {
                pub_bin = 16 * t + i;
                pub_kp  = k - (int)(cum - h[i]);       // residual rank in bin
                break;
            }
        }
    }
    __syncthreads();                                   // B4
    const uint32_t bin = (uint32_t)pub_bin;
    const int kp = pub_kp;

    // One-shot extraction: 16 independent ballots, ONE atomic per wave,
    // SALU broadcast. Positions from lanemask-below popcounts.
    uint32_t mm = 0;
    int pos[16];
    int cum = 0;
    const unsigned long long lt = (lane == 63) ? ~0ull >> 1
                                               : ((1ull << lane) - 1ull);
    #pragma unroll
    for (int e = 0; e < 16; ++e) {
        const bool m = (u[e] >> 20) == bin;
        unsigned long long mk = __ballot(m);
        pos[e] = cum + (int)__popcll(mk & ((1ull << lane) - 1ull));
        cum   += (int)__popcll(mk);
        if (m) mm |= (1u << e);
    }
    (void)lt;
    int wbase = 0;
    if (lane == 0) wbase = atomicAdd(&ns, cum);
    wbase = __builtin_amdgcn_readfirstlane(wbase);
    #pragma unroll
    for (int e = 0; e < 16; ++e)
        if (mm & (1u << e)) hist[wbase + pos[e]] = u[e];
    __syncthreads();                                   // B5
    const int N = ns;

    // Sub-select kp-th largest among N survivors by low-20 bits.
    // Redundant per wave (no barriers). mid >= 1 always, so sentinel 0 is inert.
    uint32_t lo = 0, hi = 0xFFFFFu;
    if (N <= 256) {
        uint32_t v[4];
        #pragma unroll
        for (int c = 0; c < 4; ++c) {
            int idx = 64 * c + lane;
            v[c] = (idx < N) ? (hist[idx] & 0xFFFFFu) : 0u;
        }
        #pragma unroll 1
        while (lo < hi) {
            uint32_t mid = lo + ((hi - lo + 1u) >> 1);
            int c = 0;
            #pragma unroll
            for (int j = 0; j < 4; ++j)
                c += (int)__popcll(__ballot(v[j] >= mid));
            if (c >= kp) lo = mid; else hi = mid - 1u;
        }
    } else {
        #pragma unroll 1
        while (lo < hi) {
            uint32_t mid = lo + ((hi - lo + 1u) >> 1);
            int c = 0;
            for (int cb = 0; cb < N; cb += 64) {
                uint32_t vv = 0;
                if (cb + lane < N) vv = hist[cb + lane] & 0xFFFFFu;
                c += (int)__popcll(__ballot(vv >= mid));
            }
            if (c >= kp) lo = mid; else hi = mid - 1u;
        }
    }
    const uint32_t thr = (bin << 20) | lo;             // exact k-th largest pattern

    // Write output from registers.
    #pragma unroll
    for (int j = 0; j < 4; ++j) {
        float4 o;
        float* po = &o.x;
        #pragma unroll
        for (int e = 0; e < 4; ++e) {
            uint32_t uu = u[j * 4 + e];
            uint32_t f  = (uu & 0x80000000u) ? (uu ^ 0x80000000u) : ~uu;
            po[e] = (uu >= thr) ? __uint_as_float(f) : 0.0f;
        }
        orow[t + j * THREADS] = o;
    }
}

extern "C" void kernel_launch(void* const* d_in, const int* in_sizes, int n_in,
                              void* d_out, int out_size, void* d_ws, size_t ws_size,
                              hipStream_t stream) {
    const float* x    = (const float*)d_in[0];
    const int*   kptr = (const int*)d_in[1];
    float*       out  = (float*)d_out;
    const int rows = out_size / D_DIM;   // 8192
    kwta_kernel<<<rows, THREADS, 0, stream>>>(x, kptr, out);
}